// Round 1
// baseline (35551.724 us; speedup 1.0000x reference)
//
#include <hip/hip_runtime.h>
#include <cstdint>

#define TSTEPS 8192   // B*T sequential steps
#define HH 512
#define GG 16         // workgroups in sequential kernel
#define RW 32         // hidden rows per WG
#define NT 512        // threads per WG (8 waves)

// ---------------------------------------------------------------------------
// Kernel A: GX[t][j] = Wcat[j][512:1024] . x_t + bcat[j]   (j: 0..511 r, 512..1023 z, 1024..1535 h)
// C[8192][1536] = X[8192][512] @ Wx^T, fp32, 128x128 tile, BK=32, 8x8 per thread.
// ---------------------------------------------------------------------------
__global__ __launch_bounds__(256) void gx_gemm(
    const float* __restrict__ X,
    const float* __restrict__ Wr, const float* __restrict__ br,
    const float* __restrict__ Wz, const float* __restrict__ bz,
    const float* __restrict__ Wh, const float* __restrict__ bh,
    float* __restrict__ GX)
{
    __shared__ float Xs[32][132];   // [k][m], +4 pad keeps float4 alignment & spreads banks
    __shared__ float Ws[32][132];
    const int tid = threadIdx.x;
    const int tx = tid & 15, ty = tid >> 4;
    const int t0 = blockIdx.x * 128;
    const int j0 = blockIdx.y * 128;
    const int mat = j0 >> 9;        // tile never straddles a matrix (512 % 128 == 0)
    const int jm  = j0 & 511;
    const float* W    = (mat == 0) ? Wr : (mat == 1 ? Wz : Wh);
    const float* bias = (mat == 0) ? br : (mat == 1 ? bz : bh);

    float acc[8][8];
#pragma unroll
    for (int i = 0; i < 8; i++)
#pragma unroll
        for (int j = 0; j < 8; j++) acc[i][j] = 0.f;

    for (int k0 = 0; k0 < 512; k0 += 32) {
#pragma unroll
        for (int i = 0; i < 4; i++) {
            int q = tid + 256 * i;
            int m = q >> 3, kc = q & 7;
            float4 xv = *(const float4*)(X + (size_t)(t0 + m) * 512 + k0 + kc * 4);
            Xs[kc*4+0][m] = xv.x; Xs[kc*4+1][m] = xv.y;
            Xs[kc*4+2][m] = xv.z; Xs[kc*4+3][m] = xv.w;
            float4 wv = *(const float4*)(W + (size_t)(jm + m) * 1024 + 512 + k0 + kc * 4);
            Ws[kc*4+0][m] = wv.x; Ws[kc*4+1][m] = wv.y;
            Ws[kc*4+2][m] = wv.z; Ws[kc*4+3][m] = wv.w;
        }
        __syncthreads();
#pragma unroll
        for (int kk = 0; kk < 32; kk++) {
            float a[8], b[8];
            *(float4*)&a[0] = *(const float4*)&Xs[kk][ty*8];
            *(float4*)&a[4] = *(const float4*)&Xs[kk][ty*8+4];
            *(float4*)&b[0] = *(const float4*)&Ws[kk][tx*8];
            *(float4*)&b[4] = *(const float4*)&Ws[kk][tx*8+4];
#pragma unroll
            for (int i = 0; i < 8; i++)
#pragma unroll
                for (int j = 0; j < 8; j++)
                    acc[i][j] = fmaf(a[i], b[j], acc[i][j]);
        }
        __syncthreads();
    }
#pragma unroll
    for (int i = 0; i < 8; i++) {
        int t = t0 + ty * 8 + i;
#pragma unroll
        for (int j = 0; j < 8; j += 4) {
            int jl = tx * 8 + j;
            float4 o;
            o.x = acc[i][j+0] + bias[jm + jl + 0];
            o.y = acc[i][j+1] + bias[jm + jl + 1];
            o.z = acc[i][j+2] + bias[jm + jl + 2];
            o.w = acc[i][j+3] + bias[jm + jl + 3];
            *(float4*)(GX + (size_t)t * 1536 + j0 + jl) = o;
        }
    }
}

// ---------------------------------------------------------------------------
// Kernel B: persistent sequential GRU. 16 WGs x 512 threads; WG g owns rows
// [32g, 32g+32) of r/z/cand. h-part weights live in registers (96 fp32/thread).
// Exchanges use tagged 64-bit agent-scope atomics: (step<<32)|bits(value).
// 0xAAAAAAAA poison never matches a step tag in [1,8192] -> no memset needed.
// ---------------------------------------------------------------------------
__device__ __forceinline__ float sigmoidf_(float x) { return 1.f / (1.f + __expf(-x)); }
__device__ __forceinline__ int   chix(int i)        { return (i >> 5) * 36 + (i & 31); } // padded LDS layout

__global__ __launch_bounds__(NT) void gru_seq(
    const float* __restrict__ hidden0,
    const float* __restrict__ Wr,
    const float* __restrict__ Wz,
    const float* __restrict__ Wh,
    const float* __restrict__ GX,
    unsigned long long* __restrict__ ubuf,   // [512] tagged u = r*h
    unsigned long long* __restrict__ hbuf,   // [512] tagged h_new
    float* __restrict__ out)
{
    const int tid   = threadIdx.x;
    const int g     = blockIdx.x;
    const int row_l = tid >> 4;          // 0..31
    const int sub   = tid & 15;          // 16 threads per row, 32 K-elems each
    const int grow  = g * RW + row_l;    // global hidden row owned

    __shared__ float h_s[16 * 36];       // full h, chunk-padded (stride 36) to break bank conflicts
    __shared__ float u_s[16 * 36];       // full r*h, same layout
    __shared__ int   s_dead;

    // ---- weights -> registers (h-part = cols [0,512) of [512][1024] row-major; cat order [h; x])
    float wr[32], wz[32], wh[32];
    {
        const float* pr = Wr + (size_t)grow * 1024 + sub * 32;
        const float* pz = Wz + (size_t)grow * 1024 + sub * 32;
        const float* ph = Wh + (size_t)grow * 1024 + sub * 32;
#pragma unroll
        for (int j = 0; j < 8; j++) {
            float4 a = *(const float4*)(pr + 4*j);
            wr[4*j+0]=a.x; wr[4*j+1]=a.y; wr[4*j+2]=a.z; wr[4*j+3]=a.w;
            float4 b = *(const float4*)(pz + 4*j);
            wz[4*j+0]=b.x; wz[4*j+1]=b.y; wz[4*j+2]=b.z; wz[4*j+3]=b.w;
            float4 c = *(const float4*)(ph + 4*j);
            wh[4*j+0]=c.x; wh[4*j+1]=c.y; wh[4*j+2]=c.z; wh[4*j+3]=c.w;
        }
    }
    if (tid == 0) s_dead = 0;
    if (tid < HH) h_s[chix(tid)] = hidden0[tid];
    __syncthreads();

    // gx prefetch for step 1 (owner lanes only)
    float gr = 0.f, gz = 0.f, gh = 0.f;
    if (sub == 0) { gr = GX[grow]; gz = GX[512 + grow]; gh = GX[1024 + grow]; }

    for (int s = 1; s <= TSTEPS; s++) {
        // prefetch gx for next step (consumed next iteration -> HBM latency hidden)
        float ngr = 0.f, ngz = 0.f, ngh = 0.f;
        if (sub == 0 && s < TSTEPS) {
            const float* gx2 = GX + (size_t)s * 1536;
            ngr = gx2[grow]; ngz = gx2[512 + grow]; ngh = gx2[1024 + grow];
        }
        float h_own = 0.f;
        if (sub == 0) h_own = h_s[chix(grow)];

        // ---- phase 1: r,z row-dots (h from LDS, weights in regs; r and z share each h load)
        float ar = 0.f, az = 0.f;
#pragma unroll
        for (int j = 0; j < 8; j++) {
            float4 hv = *(const float4*)&h_s[sub * 36 + 4*j];
            ar = fmaf(wr[4*j+0], hv.x, ar); az = fmaf(wz[4*j+0], hv.x, az);
            ar = fmaf(wr[4*j+1], hv.y, ar); az = fmaf(wz[4*j+1], hv.y, az);
            ar = fmaf(wr[4*j+2], hv.z, ar); az = fmaf(wz[4*j+2], hv.z, az);
            ar = fmaf(wr[4*j+3], hv.w, ar); az = fmaf(wz[4*j+3], hv.w, az);
        }
#pragma unroll
        for (int off = 8; off >= 1; off >>= 1) {
            ar += __shfl_xor(ar, off);
            az += __shfl_xor(az, off);
        }
        float zval = 0.f;
        if (sub == 0) {
            float r = sigmoidf_(ar + gr);
            zval    = sigmoidf_(az + gz);
            float u = r * h_own;
            unsigned long long pk =
                ((unsigned long long)(unsigned int)s << 32) | (unsigned long long)__float_as_uint(u);
            __hip_atomic_store(&ubuf[grow], pk, __ATOMIC_RELAXED, __HIP_MEMORY_SCOPE_AGENT);
        }
        // ---- exchange 1: poll tagged u (each thread one element)
        {
            const unsigned int want = (unsigned int)s;
            unsigned long long pk; int spins = 0;
            do {
                pk = __hip_atomic_load(&ubuf[tid], __ATOMIC_RELAXED, __HIP_MEMORY_SCOPE_AGENT);
            } while ((unsigned int)(pk >> 32) != want && ++spins < 2000000);
            if (spins >= 2000000) s_dead = 1;
            u_s[chix(tid)] = __uint_as_float((unsigned int)pk);
        }
        __syncthreads();   // u_s ready; everyone past phase-1 h_s reads

        // ---- phase 2: cand row-dots on u
        float ah = 0.f;
#pragma unroll
        for (int j = 0; j < 8; j++) {
            float4 uv = *(const float4*)&u_s[sub * 36 + 4*j];
            ah = fmaf(wh[4*j+0], uv.x, ah);
            ah = fmaf(wh[4*j+1], uv.y, ah);
            ah = fmaf(wh[4*j+2], uv.z, ah);
            ah = fmaf(wh[4*j+3], uv.w, ah);
        }
#pragma unroll
        for (int off = 8; off >= 1; off >>= 1) ah += __shfl_xor(ah, off);
        if (sub == 0) {
            float cand = tanhf(ah + gh);
            float hn   = (1.f - zval) * h_own + zval * cand;
            unsigned long long pk =
                ((unsigned long long)(unsigned int)s << 32) | (unsigned long long)__float_as_uint(hn);
            __hip_atomic_store(&hbuf[grow], pk, __ATOMIC_RELAXED, __HIP_MEMORY_SCOPE_AGENT);
        }
        // ---- exchange 2: poll tagged h_new
        {
            const unsigned int want = (unsigned int)s;
            unsigned long long pk; int spins = 0;
            do {
                pk = __hip_atomic_load(&hbuf[tid], __ATOMIC_RELAXED, __HIP_MEMORY_SCOPE_AGENT);
            } while ((unsigned int)(pk >> 32) != want && ++spins < 2000000);
            if (spins >= 2000000) s_dead = 1;
            h_s[chix(tid)] = __uint_as_float((unsigned int)pk);
        }
        __syncthreads();   // h_s ready for next step
        if (s_dead != 0) break;   // uniform (all writes precede a barrier) -> safe bail, no hang

        gr = ngr; gz = ngz; gh = ngh;
    }

    if (g == 0 && tid < HH) {
        float v = h_s[chix(tid)];
        out[tid]      = v;   // output
        out[HH + tid] = v;   // hidden (reference returns the same vector twice)
    }
}

// ---------------------------------------------------------------------------
extern "C" void kernel_launch(void* const* d_in, const int* in_sizes, int n_in,
                              void* d_out, int out_size, void* d_ws, size_t ws_size,
                              hipStream_t stream) {
    const float* emb = (const float*)d_in[0];   // [4][2048][512] -> [8192][512]
    const float* h0  = (const float*)d_in[1];   // [512]
    const float* Wr  = (const float*)d_in[2];   // [512][1024]
    const float* br  = (const float*)d_in[3];
    const float* Wz  = (const float*)d_in[4];
    const float* bz  = (const float*)d_in[5];
    const float* bh_ = (const float*)d_in[7];
    const float* Wh  = (const float*)d_in[6];
    float* out = (float*)d_out;

    float* GX = (float*)d_ws;                                  // 8192*1536 fp32 = 50.3 MB
    const size_t GXB = (size_t)8192 * 1536 * sizeof(float);
    unsigned long long* ubuf = (unsigned long long*)((char*)d_ws + GXB);  // [512]
    unsigned long long* hbuf = ubuf + 512;                                // [512]

    dim3 gA(8192 / 128, 1536 / 128);
    gx_gemm<<<gA, 256, 0, stream>>>(emb, Wr, br, Wz, bz, Wh, bh_, GX);
    gru_seq<<<GG, NT, 0, stream>>>(h0, Wr, Wz, Wh, GX, ubuf, hbuf, out);
}